// Round 1
// baseline (693.000 us; speedup 1.0000x reference)
//
#include <hip/hip_runtime.h>
#include <hip/hip_bf16.h>
#include <stdint.h>

// ---------------------------------------------------------------------------
// SelfAttention QKV projection + head-indexed RoPE, MI355X (gfx950)
//   q = rope(x @ Wq), k = rope(x @ Wk), v = x @ Wv
//   x: (16384, 2048) f32 row-major; W: (2048, 2048) f32 row-major (K x N)
//   out: q||k||v, each (16384, 2048) f32
// Strategy: bf16 MFMA GEMM (threshold budgets bf16), fused RoPE epilogue.
// d_ws usage: 3 x 8 MiB for bf16 W^T (N x K) — prepped per launch.
// ---------------------------------------------------------------------------

typedef __attribute__((ext_vector_type(8))) short short8;
typedef __attribute__((ext_vector_type(4))) float f32x4;

__device__ __forceinline__ unsigned short f2bf(float f) {
  __bf16 h = (__bf16)f;                       // RNE, compiler emits v_cvt_pk when it can
  return __builtin_bit_cast(unsigned short, h);
}

__device__ __forceinline__ void gload_lds16(const void* g, void* l) {
  __builtin_amdgcn_global_load_lds((const __attribute__((address_space(1))) void*)g,
                                   (__attribute__((address_space(3))) void*)l,
                                   16, 0, 0);
}

// W (2048x2048 f32, row-major K x N) -> WT (2048x2048 bf16, row-major N x K)
__global__ __launch_bounds__(256) void transpose_cvt(const float* __restrict__ W,
                                                     unsigned short* __restrict__ WT) {
  __shared__ unsigned short tile[64][65];     // +1 pad: conflict-free column reads
  const int bx = blockIdx.x * 64;             // N origin (col of W)
  const int by = blockIdx.y * 64;             // K origin (row of W)
  const int t  = threadIdx.x;
  const int tr = t >> 4;                      // 0..15
  const int tc = (t & 15) * 4;                // 0..60
#pragma unroll
  for (int i = 0; i < 4; ++i) {
    const int r = tr + i * 16;
    const float4 v = *(const float4*)&W[(size_t)(by + r) * 2048 + bx + tc];
    tile[r][tc + 0] = f2bf(v.x);
    tile[r][tc + 1] = f2bf(v.y);
    tile[r][tc + 2] = f2bf(v.z);
    tile[r][tc + 3] = f2bf(v.w);
  }
  __syncthreads();
#pragma unroll
  for (int i = 0; i < 4; ++i) {
    const int a = tr + i * 16;                // WT row (N index) within tile
    ushort4 o;
    o.x = tile[tc + 0][a];
    o.y = tile[tc + 1][a];
    o.z = tile[tc + 2][a];
    o.w = tile[tc + 3][a];
    *(ushort4*)&WT[(size_t)(bx + a) * 2048 + by + tc] = o;
  }
}

// 128x128 tile GEMM, BK=64, 4 waves (2x2), mfma_f32_16x16x32_bf16.
// A (x) reg-staged f32->bf16; B (W^T bf16) via global_load_lds with
// inverse-swizzled source. Both LDS tiles use byte ^= ((row&7)<<4) swizzle.
__global__ __launch_bounds__(256) void qkv_gemm(const float* __restrict__ X,
                                                const unsigned short* __restrict__ WT,
                                                float* __restrict__ Out,
                                                const int do_rope) {
  __shared__ unsigned short As[128 * 64];     // 16 KiB, swizzled [row][k]
  __shared__ unsigned short Bs[128 * 64];     // 16 KiB, swizzled [n][k]
  const int t    = threadIdx.x;
  const int wave = t >> 6, lane = t & 63;
  const int l15  = lane & 15, lg = lane >> 4;
  const int wm   = (wave >> 1) * 64;          // wave row offset in tile
  const int wn   = (wave & 1) * 64;           // wave col offset in tile
  const int m0   = blockIdx.y * 128;
  const int n0   = blockIdx.x * 128;

  f32x4 acc[4][4] = {};

  for (int kt = 0; kt < 2048; kt += 64) {
    // ---- stage A: 128x64 f32 -> bf16, swizzled ds_write ----
#pragma unroll
    for (int i = 0; i < 8; ++i) {
      const int f = i * 256 + t;
      const int row = f >> 4, chunk = f & 15;              // chunk = 4-float group
      const float4 v = *(const float4*)&X[(size_t)(m0 + row) * 2048 + kt + chunk * 4];
      const uint32_t lo = (uint32_t)f2bf(v.x) | ((uint32_t)f2bf(v.y) << 16);
      const uint32_t hi = (uint32_t)f2bf(v.z) | ((uint32_t)f2bf(v.w) << 16);
      const int slot = chunk >> 1;                          // 16B slot 0..7
      const int off  = row * 128 + (((slot ^ (row & 7)) << 4) | ((chunk & 1) << 3));
      uint2* p = (uint2*)((char*)As + off);
      p->x = lo; p->y = hi;
    }
    // ---- stage B: global_load_lds, linear LDS dest + inverse-swizzled source ----
#pragma unroll
    for (int i = 0; i < 4; ++i) {
      const int seg = i * 4 + wave;                         // 1 KiB LDS segment
      const int row = seg * 8 + (lane >> 3);                // n-row 0..127
      const int ps  = lane & 7;                             // physical slot
      const int ss  = ps ^ (row & 7);                       // source logical slot
      gload_lds16(WT + (size_t)(n0 + row) * 2048 + kt + ss * 8,
                  (char*)Bs + seg * 1024 + lane * 16);
    }
    __syncthreads();
    // ---- compute: 2 x (8 ds_read_b128 + 16 MFMA) ----
#pragma unroll
    for (int kk = 0; kk < 2; ++kk) {
      short8 afr[4], bfr[4];
#pragma unroll
      for (int mi = 0; mi < 4; ++mi) {
        const int row  = wm + mi * 16 + l15;
        const int slot = kk * 4 + lg;
        afr[mi] = *(const short8*)((const char*)As + row * 128 + ((slot ^ (row & 7)) << 4));
      }
#pragma unroll
      for (int ni = 0; ni < 4; ++ni) {
        const int row  = wn + ni * 16 + l15;
        const int slot = kk * 4 + lg;
        bfr[ni] = *(const short8*)((const char*)Bs + row * 128 + ((slot ^ (row & 7)) << 4));
      }
#pragma unroll
      for (int mi = 0; mi < 4; ++mi)
#pragma unroll
        for (int ni = 0; ni < 4; ++ni)
          asm("v_mfma_f32_16x16x32_bf16 %0, %1, %2, %0"
              : "+v"(acc[mi][ni])
              : "v"(afr[mi]), "v"(bfr[ni]));
    }
    __syncthreads();
  }

  // ---- epilogue: fused RoPE (pos = head index h = col>>7, pair p = (col&127)>>1)
  // C layout: col = lane&15, row = (lane>>4)*4 + reg. Partner column = lane^1.
#pragma unroll
  for (int ni = 0; ni < 4; ++ni) {
    const int col = n0 + wn + ni * 16 + l15;
    float c = 1.0f, ssg = 0.0f;
    if (do_rope) {
      const int h = col >> 7;
      const int p = (col & 127) >> 1;
      const float theta = exp2f(-(float)p * 0.20762050593046014f);  // log2(1e4)/64
      float s;
      sincosf((float)h * theta, &s, &c);
      ssg = (l15 & 1) ? s : -s;   // even col: re = v*c - o*s ; odd col: ro = o*s + v*c
    }
#pragma unroll
    for (int mi = 0; mi < 4; ++mi) {
      const f32x4 a = acc[mi][ni];
#pragma unroll
      for (int r = 0; r < 4; ++r) {
        const float val = a[r];
        float res = val;
        if (do_rope) {
          const float other = __shfl_xor(val, 1);
          res = val * c + other * ssg;
        }
        Out[(size_t)(m0 + wm + mi * 16 + lg * 4 + r) * 2048 + col] = res;
      }
    }
  }
}

extern "C" void kernel_launch(void* const* d_in, const int* in_sizes, int n_in,
                              void* d_out, int out_size, void* d_ws, size_t ws_size,
                              hipStream_t stream) {
  (void)in_sizes; (void)n_in; (void)out_size; (void)ws_size;
  const float* x  = (const float*)d_in[0];
  const float* Wq = (const float*)d_in[1];
  const float* Wk = (const float*)d_in[2];
  const float* Wv = (const float*)d_in[3];
  // d_in[4] = st_pos, unused by the reference math.
  float* out = (float*)d_out;

  unsigned short* WqT = (unsigned short*)d_ws;        // 3 x 8 MiB bf16 W^T
  unsigned short* WkT = WqT + 2048 * 2048;
  unsigned short* WvT = WkT + 2048 * 2048;

  dim3 tb(256), tg(32, 32);
  transpose_cvt<<<tg, tb, 0, stream>>>(Wq, WqT);
  transpose_cvt<<<tg, tb, 0, stream>>>(Wk, WkT);
  transpose_cvt<<<tg, tb, 0, stream>>>(Wv, WvT);

  dim3 gg(16, 128);   // (N/128, M/128)
  qkv_gemm<<<gg, tb, 0, stream>>>(x, WqT, out,            1);
  qkv_gemm<<<gg, tb, 0, stream>>>(x, WkT, out + 33554432, 1);
  qkv_gemm<<<gg, tb, 0, stream>>>(x, WvT, out + 67108864, 0);
}

// Round 2
// 643.763 us; speedup vs baseline: 1.0765x; 1.0765x over previous
//
#include <hip/hip_runtime.h>
#include <hip/hip_bf16.h>
#include <stdint.h>

// ---------------------------------------------------------------------------
// SelfAttention QKV projection + head-indexed RoPE, MI355X (gfx950)
//   q = rope(x @ Wq), k = rope(x @ Wk), v = x @ Wv   (pos = head index!)
//   x: (16384, 2048) f32; W: (2048, 2048) f32 (K x N); out: q||k||v f32
// Round 2: pre-convert x->bf16 + W->bf16^T into ws, ONE fused GEMM
//   (M=16384, N=6144, K=2048), 256x256 tile, BK=32, 8 waves, dbuf LDS,
//   counted-prefetch schedule (stage early, drain covered by MFMA), XCD
//   swizzle, double-XOR LDS swizzle, fused RoPE epilogue.
// ---------------------------------------------------------------------------

typedef __attribute__((ext_vector_type(8))) short short8;
typedef __attribute__((ext_vector_type(4))) float f32x4;

__device__ __forceinline__ unsigned short f2bf(float f) {
  __bf16 h = (__bf16)f;
  return __builtin_bit_cast(unsigned short, h);
}

__device__ __forceinline__ void gload_lds16(const void* g, void* l) {
  __builtin_amdgcn_global_load_lds((const __attribute__((address_space(1))) void*)g,
                                   (__attribute__((address_space(3))) void*)l,
                                   16, 0, 0);
}

// ---------------- prep kernels ----------------

// x f32 -> bf16, 8 elems/thread/iter
__global__ __launch_bounds__(256) void convert_x(const float* __restrict__ X,
                                                 unsigned short* __restrict__ Xb,
                                                 int n8) {
  const int stride = gridDim.x * blockDim.x;
  for (int i = blockIdx.x * blockDim.x + threadIdx.x; i < n8; i += stride) {
    const float4 v0 = ((const float4*)X)[(size_t)i * 2 + 0];
    const float4 v1 = ((const float4*)X)[(size_t)i * 2 + 1];
    uint4 w;
    w.x = (uint32_t)f2bf(v0.x) | ((uint32_t)f2bf(v0.y) << 16);
    w.y = (uint32_t)f2bf(v0.z) | ((uint32_t)f2bf(v0.w) << 16);
    w.z = (uint32_t)f2bf(v1.x) | ((uint32_t)f2bf(v1.y) << 16);
    w.w = (uint32_t)f2bf(v1.z) | ((uint32_t)f2bf(v1.w) << 16);
    ((uint4*)Xb)[i] = w;
  }
}

// W (2048x2048 f32, K x N) -> WT (bf16, N x K)
__global__ __launch_bounds__(256) void transpose_cvt(const float* __restrict__ W,
                                                     unsigned short* __restrict__ WT) {
  __shared__ unsigned short tile[64][65];
  const int bx = blockIdx.x * 64;             // N origin
  const int by = blockIdx.y * 64;             // K origin
  const int t  = threadIdx.x;
  const int tr = t >> 4;
  const int tc = (t & 15) * 4;
#pragma unroll
  for (int i = 0; i < 4; ++i) {
    const int r = tr + i * 16;
    const float4 v = *(const float4*)&W[(size_t)(by + r) * 2048 + bx + tc];
    tile[r][tc + 0] = f2bf(v.x);
    tile[r][tc + 1] = f2bf(v.y);
    tile[r][tc + 2] = f2bf(v.z);
    tile[r][tc + 3] = f2bf(v.w);
  }
  __syncthreads();
#pragma unroll
  for (int i = 0; i < 4; ++i) {
    const int a = tr + i * 16;
    ushort4 o;
    o.x = tile[tc + 0][a];
    o.y = tile[tc + 1][a];
    o.z = tile[tc + 2][a];
    o.w = tile[tc + 3][a];
    *(ushort4*)&WT[(size_t)(bx + a) * 2048 + by + tc] = o;
  }
}

// ---------------- fused 256x256 GEMM, BK=32, 8 waves ----------------
// LDS: double-buffered A(256x32) + B(256x32) bf16 = 64 KiB total.
// Swizzle: 16B slot s_phys = s_log ^ (row&3) ^ ((row>>2)&3)  (rows are 64B).
// Staged with linear LDS dest + inverse-swizzled global source (rule #21).

__global__ __launch_bounds__(512, 2) void qkv_fused(const unsigned short* __restrict__ Xb,
                                                    const unsigned short* __restrict__ WT,
                                                    float* __restrict__ Out) {
  __shared__ unsigned short As[2][256 * 32];
  __shared__ unsigned short Bs[2][256 * 32];

  // XCD-aware swizzle (1536 blocks, 1536 % 8 == 0 -> simple form is bijective)
  const int wg  = blockIdx.x;
  const int swz = (wg & 7) * 192 + (wg >> 3);
  const int mb  = swz / 24, nb = swz % 24;
  const int m0  = mb * 256, n0 = nb * 256;

  const int tid  = threadIdx.x;
  const int wave = tid >> 6, lane = tid & 63;
  const int l15  = lane & 15, lg = lane >> 4;
  const int wm   = (wave >> 2) * 128;         // 2 wave-rows
  const int wn   = (wave & 3) * 64;           // 4 wave-cols
  const int foff = ((lg ^ (l15 & 3) ^ ((l15 >> 2) & 3)) << 4);  // frag byte off

  const unsigned short* Xp = Xb + (size_t)m0 * 2048;
  const unsigned short* Wp = WT + (size_t)n0 * 2048;

  f32x4 acc[8][4] = {};

#define STAGE(KT, SEL)                                                        \
  do {                                                                        \
    const int kt_ = (KT);                                                     \
    _Pragma("unroll") for (int i = 0; i < 2; ++i) {                           \
      const int f = i * 512 + tid;                                            \
      const int row = f >> 2, sl = f & 3;                                     \
      const int ssl = sl ^ (row & 3) ^ ((row >> 2) & 3);                      \
      gload_lds16(Xp + (size_t)row * 2048 + kt_ + ssl * 8,                    \
                  (char*)&As[SEL][0] + row * 64 + sl * 16);                   \
    }                                                                         \
    _Pragma("unroll") for (int i = 0; i < 2; ++i) {                           \
      const int f = i * 512 + tid;                                            \
      const int row = f >> 2, sl = f & 3;                                     \
      const int ssl = sl ^ (row & 3) ^ ((row >> 2) & 3);                      \
      gload_lds16(Wp + (size_t)row * 2048 + kt_ + ssl * 8,                    \
                  (char*)&Bs[SEL][0] + row * 64 + sl * 16);                   \
    }                                                                         \
  } while (0)

  // prologue: stage tile 0
  STAGE(0, 0);
  asm volatile("s_waitcnt vmcnt(0)" ::: "memory");
  __builtin_amdgcn_s_barrier();

  for (int tt = 0; tt < 64; ++tt) {
    const int cur = tt & 1;
    if (tt + 1 < 64) STAGE((tt + 1) * 32, cur ^ 1);   // prefetch next tile

    const char* Ab = (const char*)&As[cur][0];
    const char* Bb = (const char*)&Bs[cur][0];
    short8 af[8], bf[4];
#pragma unroll
    for (int mi = 0; mi < 8; ++mi)
      af[mi] = *(const short8*)(Ab + (wm + mi * 16 + l15) * 64 + foff);
#pragma unroll
    for (int ni = 0; ni < 4; ++ni)
      bf[ni] = *(const short8*)(Bb + (wn + ni * 16 + l15) * 64 + foff);

    __builtin_amdgcn_s_setprio(1);
#pragma unroll
    for (int mi = 0; mi < 8; ++mi)
#pragma unroll
      for (int ni = 0; ni < 4; ++ni)
        asm("v_mfma_f32_16x16x32_bf16 %0, %1, %2, %0"
            : "+v"(acc[mi][ni])
            : "v"(af[mi]), "v"(bf[ni]));
    __builtin_amdgcn_s_setprio(0);

    // boundary: next tile's loads were issued ~1500 cyc ago -> drain ~free
    asm volatile("s_waitcnt vmcnt(0)" ::: "memory");
    __builtin_amdgcn_s_barrier();
  }
#undef STAGE

  // epilogue: fused RoPE. C layout: col=lane&15, row=(lane>>4)*4+reg.
#pragma unroll
  for (int ni = 0; ni < 4; ++ni) {
    const int col = n0 + wn + ni * 16 + l15;
    const int sec = col >> 11;                 // 0=q,1=k,2=v
    const int lc  = col & 2047;
    float c = 1.0f, ssg = 0.0f;
    if (sec < 2) {
      const int h = lc >> 7;
      const int p = (lc & 127) >> 1;
      const float theta = exp2f(-(float)p * 0.20762050593046014f); // log2(1e4)/64
      float s;
      sincosf((float)h * theta, &s, &c);
      ssg = (l15 & 1) ? s : -s;
    }
    float* outp = Out + (size_t)sec * 33554432 + lc;
#pragma unroll
    for (int mi = 0; mi < 8; ++mi) {
      const f32x4 a = acc[mi][ni];
#pragma unroll
      for (int r = 0; r < 4; ++r) {
        const float val = a[r];
        float res = val;
        if (sec < 2) {
          const float other = __shfl_xor(val, 1);
          res = val * c + other * ssg;
        }
        outp[(size_t)(m0 + wm + mi * 16 + lg * 4 + r) * 2048] = res;
      }
    }
  }
}

// ---------------- round-1 fallback GEMM (ws too small) ----------------
__global__ __launch_bounds__(256) void qkv_gemm_small(const float* __restrict__ X,
                                                      const unsigned short* __restrict__ WTl,
                                                      float* __restrict__ Out,
                                                      const int do_rope) {
  __shared__ unsigned short As[128 * 64];
  __shared__ unsigned short Bs[128 * 64];
  const int t    = threadIdx.x;
  const int wave = t >> 6, lane = t & 63;
  const int l15  = lane & 15, lg = lane >> 4;
  const int wm   = (wave >> 1) * 64;
  const int wn   = (wave & 1) * 64;
  const int m0   = blockIdx.y * 128;
  const int n0   = blockIdx.x * 128;

  f32x4 acc[4][4] = {};

  for (int kt = 0; kt < 2048; kt += 64) {
#pragma unroll
    for (int i = 0; i < 8; ++i) {
      const int f = i * 256 + t;
      const int row = f >> 4, chunk = f & 15;
      const float4 v = *(const float4*)&X[(size_t)(m0 + row) * 2048 + kt + chunk * 4];
      const uint32_t lo = (uint32_t)f2bf(v.x) | ((uint32_t)f2bf(v.y) << 16);
      const uint32_t hi = (uint32_t)f2bf(v.z) | ((uint32_t)f2bf(v.w) << 16);
      const int slot = chunk >> 1;
      const int off  = row * 128 + (((slot ^ (row & 7)) << 4) | ((chunk & 1) << 3));
      uint2* p = (uint2*)((char*)As + off);
      p->x = lo; p->y = hi;
    }
#pragma unroll
    for (int i = 0; i < 4; ++i) {
      const int seg = i * 4 + wave;
      const int row = seg * 8 + (lane >> 3);
      const int ps  = lane & 7;
      const int ss  = ps ^ (row & 7);
      gload_lds16(WTl + (size_t)(n0 + row) * 2048 + kt + ss * 8,
                  (char*)Bs + seg * 1024 + lane * 16);
    }
    __syncthreads();
#pragma unroll
    for (int kk = 0; kk < 2; ++kk) {
      short8 afr[4], bfr[4];
#pragma unroll
      for (int mi = 0; mi < 4; ++mi) {
        const int row  = wm + mi * 16 + l15;
        const int slot = kk * 4 + lg;
        afr[mi] = *(const short8*)((const char*)As + row * 128 + ((slot ^ (row & 7)) << 4));
      }
#pragma unroll
      for (int ni = 0; ni < 4; ++ni) {
        const int row  = wn + ni * 16 + l15;
        const int slot = kk * 4 + lg;
        bfr[ni] = *(const short8*)((const char*)Bs + row * 128 + ((slot ^ (row & 7)) << 4));
      }
#pragma unroll
      for (int mi = 0; mi < 4; ++mi)
#pragma unroll
        for (int ni = 0; ni < 4; ++ni)
          asm("v_mfma_f32_16x16x32_bf16 %0, %1, %2, %0"
              : "+v"(acc[mi][ni])
              : "v"(afr[mi]), "v"(bfr[ni]));
    }
    __syncthreads();
  }

#pragma unroll
  for (int ni = 0; ni < 4; ++ni) {
    const int col = n0 + wn + ni * 16 + l15;
    float c = 1.0f, ssg = 0.0f;
    if (do_rope) {
      const int h = col >> 7;
      const int p = (col & 127) >> 1;
      const float theta = exp2f(-(float)p * 0.20762050593046014f);
      float s;
      sincosf((float)h * theta, &s, &c);
      ssg = (l15 & 1) ? s : -s;
    }
#pragma unroll
    for (int mi = 0; mi < 4; ++mi) {
      const f32x4 a = acc[mi][ni];
#pragma unroll
      for (int r = 0; r < 4; ++r) {
        const float val = a[r];
        float res = val;
        if (do_rope) {
          const float other = __shfl_xor(val, 1);
          res = val * c + other * ssg;
        }
        Out[(size_t)(m0 + wm + mi * 16 + lg * 4 + r) * 2048 + col] = res;
      }
    }
  }
}

extern "C" void kernel_launch(void* const* d_in, const int* in_sizes, int n_in,
                              void* d_out, int out_size, void* d_ws, size_t ws_size,
                              hipStream_t stream) {
  (void)in_sizes; (void)n_in; (void)out_size;
  const float* x  = (const float*)d_in[0];
  const float* Wq = (const float*)d_in[1];
  const float* Wk = (const float*)d_in[2];
  const float* Wv = (const float*)d_in[3];
  float* out = (float*)d_out;

  const size_t XB_ELEMS = 16384ull * 2048;
  const size_t WT_ELEMS = 6144ull * 2048;
  dim3 tb(256), tg(32, 32);

  if (ws_size >= (XB_ELEMS + WT_ELEMS) * sizeof(unsigned short)) {
    unsigned short* Xb  = (unsigned short*)d_ws;
    unsigned short* WTf = Xb + XB_ELEMS;
    convert_x<<<2048, 256, 0, stream>>>(x, Xb, (int)(XB_ELEMS / 8));
    transpose_cvt<<<tg, tb, 0, stream>>>(Wq, WTf);
    transpose_cvt<<<tg, tb, 0, stream>>>(Wk, WTf + 2048ull * 2048);
    transpose_cvt<<<tg, tb, 0, stream>>>(Wv, WTf + 2ull * 2048 * 2048);
    qkv_fused<<<1536, 512, 0, stream>>>(Xb, WTf, out);
  } else {
    unsigned short* WqT = (unsigned short*)d_ws;
    unsigned short* WkT = WqT + 2048ull * 2048;
    unsigned short* WvT = WkT + 2048ull * 2048;
    transpose_cvt<<<tg, tb, 0, stream>>>(Wq, WqT);
    transpose_cvt<<<tg, tb, 0, stream>>>(Wk, WkT);
    transpose_cvt<<<tg, tb, 0, stream>>>(Wv, WvT);
    dim3 gg(16, 128);
    qkv_gemm_small<<<gg, tb, 0, stream>>>(x, WqT, out,            1);
    qkv_gemm_small<<<gg, tb, 0, stream>>>(x, WkT, out + 33554432, 1);
    qkv_gemm_small<<<gg, tb, 0, stream>>>(x, WvT, out + 67108864, 0);
  }
}

// Round 3
// 497.180 us; speedup vs baseline: 1.3939x; 1.2948x over previous
//
#include <hip/hip_runtime.h>
#include <hip/hip_bf16.h>
#include <stdint.h>

// ---------------------------------------------------------------------------
// SelfAttention QKV projection + head-indexed RoPE, MI355X (gfx950)
//   q = rope(x @ Wq), k = rope(x @ Wk), v = x @ Wv   (pos = head index!)
// Round 3: fused GEMM (M=16384, N=6144, K=2048), 256x256 tile, BK=64,
//   8 waves, 128 KiB dbuf LDS (dynamic), (row&7)<<4 XOR swizzle on 128B rows,
//   quadrant-interleaved ds_read/MFMA with free wave drift (1 barrier/iter),
//   stage-early + single vmcnt(0) drain covered by the whole iter's MFMA.
// ---------------------------------------------------------------------------

typedef __attribute__((ext_vector_type(8))) short short8;
typedef __attribute__((ext_vector_type(4))) float f32x4;

__device__ __forceinline__ unsigned short f2bf(float f) {
  __bf16 h = (__bf16)f;
  return __builtin_bit_cast(unsigned short, h);
}

__device__ __forceinline__ void gload_lds16(const void* g, void* l) {
  __builtin_amdgcn_global_load_lds((const __attribute__((address_space(1))) void*)g,
                                   (__attribute__((address_space(3))) void*)l,
                                   16, 0, 0);
}

// ---------------- prep kernels ----------------

__global__ __launch_bounds__(256) void convert_x(const float* __restrict__ X,
                                                 unsigned short* __restrict__ Xb,
                                                 int n8) {
  const int stride = gridDim.x * blockDim.x;
  for (int i = blockIdx.x * blockDim.x + threadIdx.x; i < n8; i += stride) {
    const float4 v0 = ((const float4*)X)[(size_t)i * 2 + 0];
    const float4 v1 = ((const float4*)X)[(size_t)i * 2 + 1];
    uint4 w;
    w.x = (uint32_t)f2bf(v0.x) | ((uint32_t)f2bf(v0.y) << 16);
    w.y = (uint32_t)f2bf(v0.z) | ((uint32_t)f2bf(v0.w) << 16);
    w.z = (uint32_t)f2bf(v1.x) | ((uint32_t)f2bf(v1.y) << 16);
    w.w = (uint32_t)f2bf(v1.z) | ((uint32_t)f2bf(v1.w) << 16);
    ((uint4*)Xb)[i] = w;
  }
}

// W (2048x2048 f32, K x N) -> WT (bf16, N x K)
__global__ __launch_bounds__(256) void transpose_cvt(const float* __restrict__ W,
                                                     unsigned short* __restrict__ WT) {
  __shared__ unsigned short tile[64][65];
  const int bx = blockIdx.x * 64;             // N origin
  const int by = blockIdx.y * 64;             // K origin
  const int t  = threadIdx.x;
  const int tr = t >> 4;
  const int tc = (t & 15) * 4;
#pragma unroll
  for (int i = 0; i < 4; ++i) {
    const int r = tr + i * 16;
    const float4 v = *(const float4*)&W[(size_t)(by + r) * 2048 + bx + tc];
    tile[r][tc + 0] = f2bf(v.x);
    tile[r][tc + 1] = f2bf(v.y);
    tile[r][tc + 2] = f2bf(v.z);
    tile[r][tc + 3] = f2bf(v.w);
  }
  __syncthreads();
#pragma unroll
  for (int i = 0; i < 4; ++i) {
    const int a = tr + i * 16;
    ushort4 o;
    o.x = tile[tc + 0][a];
    o.y = tile[tc + 1][a];
    o.z = tile[tc + 2][a];
    o.w = tile[tc + 3][a];
    *(ushort4*)&WT[(size_t)(bx + a) * 2048 + by + tc] = o;
  }
}

// ---------------- fused 256x256 GEMM, BK=64, 8 waves, 128 KiB LDS ----------
// LDS rows are 128 B (64 bf16). Swizzle: 16B slot s_phys = s_log ^ (row&7).
// Frag read slot = (kk*4+lg) ^ (l15&7)  -> 8 bank-quads x 2 lanes (free).
// Staged with linear gload_lds dest + inverse-swizzled global source.

__global__ __launch_bounds__(512, 2) void qkv_fused8(const unsigned short* __restrict__ Xb,
                                                     const unsigned short* __restrict__ WT,
                                                     float* __restrict__ Out) {
  extern __shared__ char smem[];
  char* A0 = smem;             char* B0 = smem + 32768;
  char* A1 = smem + 65536;     char* B1 = smem + 98304;

  // XCD-aware swizzle (1536 blocks, 1536 % 8 == 0 -> bijective)
  const int wg  = blockIdx.x;
  const int swz = (wg & 7) * 192 + (wg >> 3);
  const int mb  = swz / 24, nb = swz % 24;
  const int m0  = mb * 256, n0 = nb * 256;

  const int tid  = threadIdx.x;
  const int wave = tid >> 6, lane = tid & 63;
  const int l15  = lane & 15, lg = lane >> 4;
  const int wm   = (wave >> 2) * 128;          // 2 wave-rows
  const int wn   = (wave & 3) * 64;            // 4 wave-cols
  const int s0   = ((lg ^ (l15 & 7)) << 4);    // kk=0 frag slot byte; kk=1: s0^64

  const unsigned short* Xp = Xb + (size_t)m0 * 2048;
  const unsigned short* Wp = WT + (size_t)n0 * 2048;

  const int srow  = tid >> 3;                  // staging row within 64-row group
  const int sslot = tid & 7;                   // physical 16B slot

  f32x4 acc[8][4] = {};

#define STAGE(KT, AB, BB)                                                     \
  do {                                                                        \
    const int kt_ = (KT);                                                     \
    _Pragma("unroll") for (int i = 0; i < 4; ++i) {                           \
      const int row = i * 64 + srow;                                          \
      gload_lds16(Xp + (size_t)row * 2048 + kt_ + ((sslot ^ (row & 7)) << 3), \
                  (AB) + i * 8192 + tid * 16);                                \
    }                                                                         \
    _Pragma("unroll") for (int i = 0; i < 4; ++i) {                           \
      const int row = i * 64 + srow;                                          \
      gload_lds16(Wp + (size_t)row * 2048 + kt_ + ((sslot ^ (row & 7)) << 3), \
                  (BB) + i * 8192 + tid * 16);                                \
    }                                                                         \
  } while (0)

#define LDA(DST, MI, ABASE)                                                   \
  do {                                                                        \
    const char* p_ = (ABASE) + ((wm + (MI) * 16 + l15) << 7);                 \
    (DST)[0] = *(const short8*)(p_ + s0);                                     \
    (DST)[1] = *(const short8*)(p_ + (s0 ^ 64));                              \
  } while (0)

#define MFMAQ(Q, AR)                                                          \
  do {                                                                        \
    __builtin_amdgcn_s_setprio(1);                                            \
    _Pragma("unroll") for (int mi2 = 0; mi2 < 2; ++mi2)                       \
      _Pragma("unroll") for (int ni = 0; ni < 4; ++ni) {                      \
        asm("v_mfma_f32_16x16x32_bf16 %0, %1, %2, %0"                         \
            : "+v"(acc[2 * (Q) + mi2][ni])                                    \
            : "v"((AR)[mi2][0]), "v"(bf[ni][0]));                             \
        asm("v_mfma_f32_16x16x32_bf16 %0, %1, %2, %0"                         \
            : "+v"(acc[2 * (Q) + mi2][ni])                                    \
            : "v"((AR)[mi2][1]), "v"(bf[ni][1]));                             \
      }                                                                       \
    __builtin_amdgcn_s_setprio(0);                                            \
  } while (0)

  // prologue: stage tile 0
  STAGE(0, A0, B0);
  asm volatile("s_waitcnt vmcnt(0)" ::: "memory");
  __builtin_amdgcn_s_barrier();

  for (int t = 0; t < 32; ++t) {
    char* Ab = (t & 1) ? A1 : A0;
    char* Bb = (t & 1) ? B1 : B0;
    if (t < 31) {
      char* An = (t & 1) ? A0 : A1;
      char* Bn = (t & 1) ? B0 : B1;
      STAGE((t + 1) * 64, An, Bn);   // target buffer fully free this iter
    }

    short8 bf[4][2];
#pragma unroll
    for (int ni = 0; ni < 4; ++ni) {
      const char* p = Bb + ((wn + ni * 16 + l15) << 7);
      bf[ni][0] = *(const short8*)(p + s0);
      bf[ni][1] = *(const short8*)(p + (s0 ^ 64));
    }

    short8 aA[2][2], aB[2][2];
    LDA(aA[0], 0, Ab); LDA(aA[1], 1, Ab);
    LDA(aB[0], 2, Ab); LDA(aB[1], 3, Ab);
    MFMAQ(0, aA);
    LDA(aA[0], 4, Ab); LDA(aA[1], 5, Ab);
    MFMAQ(1, aB);
    LDA(aB[0], 6, Ab); LDA(aB[1], 7, Ab);
    MFMAQ(2, aA);
    MFMAQ(3, aB);

    // drain: stage was issued a full iter of compute ago
    asm volatile("s_waitcnt vmcnt(0)" ::: "memory");
    __builtin_amdgcn_s_barrier();
  }
#undef STAGE
#undef LDA
#undef MFMAQ

  // epilogue: fused RoPE. C layout: col=lane&15, row=(lane>>4)*4+reg.
#pragma unroll
  for (int ni = 0; ni < 4; ++ni) {
    const int col = n0 + wn + ni * 16 + l15;
    const int sec = col >> 11;                 // 0=q,1=k,2=v
    const int lc  = col & 2047;
    float c = 1.0f, ssg = 0.0f;
    if (sec < 2) {
      const int h = lc >> 7;
      const int p = (lc & 127) >> 1;
      const float theta = exp2f(-(float)p * 0.20762050593046014f); // log2(1e4)/64
      float s;
      sincosf((float)h * theta, &s, &c);
      ssg = (l15 & 1) ? s : -s;
    }
    float* outp = Out + (size_t)sec * 33554432 + lc;
#pragma unroll
    for (int mi = 0; mi < 8; ++mi) {
      const f32x4 a = acc[mi][ni];
#pragma unroll
      for (int r = 0; r < 4; ++r) {
        const float val = a[r];
        float res = val;
        if (sec < 2) {
          const float other = __shfl_xor(val, 1);
          res = val * c + other * ssg;
        }
        outp[(size_t)(m0 + wm + mi * 16 + lg * 4 + r) * 2048] = res;
      }
    }
  }
}

// ---------------- fallback GEMM (ws too small) ----------------
__global__ __launch_bounds__(256) void qkv_gemm_small(const float* __restrict__ X,
                                                      const unsigned short* __restrict__ WTl,
                                                      float* __restrict__ Out,
                                                      const int do_rope) {
  __shared__ unsigned short As[128 * 64];
  __shared__ unsigned short Bs[128 * 64];
  const int t    = threadIdx.x;
  const int wave = t >> 6, lane = t & 63;
  const int l15  = lane & 15, lg = lane >> 4;
  const int wm   = (wave >> 1) * 64;
  const int wn   = (wave & 1) * 64;
  const int m0   = blockIdx.y * 128;
  const int n0   = blockIdx.x * 128;

  f32x4 acc[4][4] = {};

  for (int kt = 0; kt < 2048; kt += 64) {
#pragma unroll
    for (int i = 0; i < 8; ++i) {
      const int f = i * 256 + t;
      const int row = f >> 4, chunk = f & 15;
      const float4 v = *(const float4*)&X[(size_t)(m0 + row) * 2048 + kt + chunk * 4];
      const uint32_t lo = (uint32_t)f2bf(v.x) | ((uint32_t)f2bf(v.y) << 16);
      const uint32_t hi = (uint32_t)f2bf(v.z) | ((uint32_t)f2bf(v.w) << 16);
      const int slot = chunk >> 1;
      const int off  = row * 128 + (((slot ^ (row & 7)) << 4) | ((chunk & 1) << 3));
      uint2* p = (uint2*)((char*)As + off);
      p->x = lo; p->y = hi;
    }
#pragma unroll
    for (int i = 0; i < 4; ++i) {
      const int seg = i * 4 + wave;
      const int row = seg * 8 + (lane >> 3);
      const int ps  = lane & 7;
      const int ss  = ps ^ (row & 7);
      gload_lds16(WTl + (size_t)(n0 + row) * 2048 + kt + ss * 8,
                  (char*)Bs + seg * 1024 + lane * 16);
    }
    __syncthreads();
#pragma unroll
    for (int kk = 0; kk < 2; ++kk) {
      short8 afr[4], bfr[4];
#pragma unroll
      for (int mi = 0; mi < 4; ++mi) {
        const int row  = wm + mi * 16 + l15;
        const int slot = kk * 4 + lg;
        afr[mi] = *(const short8*)((const char*)As + row * 128 + ((slot ^ (row & 7)) << 4));
      }
#pragma unroll
      for (int ni = 0; ni < 4; ++ni) {
        const int row  = wn + ni * 16 + l15;
        const int slot = kk * 4 + lg;
        bfr[ni] = *(const short8*)((const char*)Bs + row * 128 + ((slot ^ (row & 7)) << 4));
      }
#pragma unroll
      for (int mi = 0; mi < 4; ++mi)
#pragma unroll
        for (int ni = 0; ni < 4; ++ni)
          asm("v_mfma_f32_16x16x32_bf16 %0, %1, %2, %0"
              : "+v"(acc[mi][ni])
              : "v"(afr[mi]), "v"(bfr[ni]));
    }
    __syncthreads();
  }

#pragma unroll
  for (int ni = 0; ni < 4; ++ni) {
    const int col = n0 + wn + ni * 16 + l15;
    float c = 1.0f, ssg = 0.0f;
    if (do_rope) {
      const int h = col >> 7;
      const int p = (col & 127) >> 1;
      const float theta = exp2f(-(float)p * 0.20762050593046014f);
      float s;
      sincosf((float)h * theta, &s, &c);
      ssg = (l15 & 1) ? s : -s;
    }
#pragma unroll
    for (int mi = 0; mi < 4; ++mi) {
      const f32x4 a = acc[mi][ni];
#pragma unroll
      for (int r = 0; r < 4; ++r) {
        const float val = a[r];
        float res = val;
        if (do_rope) {
          const float other = __shfl_xor(val, 1);
          res = val * c + other * ssg;
        }
        Out[(size_t)(m0 + wm + mi * 16 + lg * 4 + r) * 2048 + col] = res;
      }
    }
  }
}

extern "C" void kernel_launch(void* const* d_in, const int* in_sizes, int n_in,
                              void* d_out, int out_size, void* d_ws, size_t ws_size,
                              hipStream_t stream) {
  (void)in_sizes; (void)n_in; (void)out_size;
  const float* x  = (const float*)d_in[0];
  const float* Wq = (const float*)d_in[1];
  const float* Wk = (const float*)d_in[2];
  const float* Wv = (const float*)d_in[3];
  float* out = (float*)d_out;

  const size_t XB_ELEMS = 16384ull * 2048;
  const size_t WT_ELEMS = 6144ull * 2048;
  dim3 tb(256), tg(32, 32);

  if (ws_size >= (XB_ELEMS + WT_ELEMS) * sizeof(unsigned short)) {
    unsigned short* Xb  = (unsigned short*)d_ws;
    unsigned short* WTf = Xb + XB_ELEMS;
    convert_x<<<2048, 256, 0, stream>>>(x, Xb, (int)(XB_ELEMS / 8));
    transpose_cvt<<<tg, tb, 0, stream>>>(Wq, WTf);
    transpose_cvt<<<tg, tb, 0, stream>>>(Wk, WTf + 2048ull * 2048);
    transpose_cvt<<<tg, tb, 0, stream>>>(Wv, WTf + 2ull * 2048 * 2048);
    hipFuncSetAttribute((const void*)qkv_fused8,
                        hipFuncAttributeMaxDynamicSharedMemorySize, 131072);
    qkv_fused8<<<1536, 512, 131072, stream>>>(Xb, WTf, out);
  } else {
    unsigned short* WqT = (unsigned short*)d_ws;
    unsigned short* WkT = WqT + 2048ull * 2048;
    unsigned short* WvT = WkT + 2048ull * 2048;
    transpose_cvt<<<tg, tb, 0, stream>>>(Wq, WqT);
    transpose_cvt<<<tg, tb, 0, stream>>>(Wk, WkT);
    transpose_cvt<<<tg, tb, 0, stream>>>(Wv, WvT);
    dim3 gg(16, 128);
    qkv_gemm_small<<<gg, tb, 0, stream>>>(x, WqT, out,            1);
    qkv_gemm_small<<<gg, tb, 0, stream>>>(x, WkT, out + 33554432, 1);
    qkv_gemm_small<<<gg, tb, 0, stream>>>(x, WvT, out + 67108864, 0);
  }
}

// Round 4
// 448.216 us; speedup vs baseline: 1.5461x; 1.1092x over previous
//
#include <hip/hip_runtime.h>
#include <hip/hip_bf16.h>
#include <stdint.h>

// ---------------------------------------------------------------------------
// SelfAttention QKV projection + head-indexed RoPE, MI355X (gfx950)
//   q = rope(x @ Wq), k = rope(x @ Wk), v = x @ Wv   (pos = head index!)
// Round 4: fused GEMM (M=16384, N=6144, K=2048), 256x256 tile, 8 waves,
//   K=32 subtiles QUAD-buffered (128 KiB LDS), pipeline depth 3 with
//   COUNTED s_waitcnt vmcnt(8) (never drain-0 in main loop), one barrier
//   per subtile, XOR bank swizzle, XCD swizzle, nontemporal f32 stores,
//   fused RoPE epilogue.
// ---------------------------------------------------------------------------

typedef __attribute__((ext_vector_type(8))) short short8;
typedef __attribute__((ext_vector_type(4))) float f32x4;

__device__ __forceinline__ unsigned short f2bf(float f) {
  __bf16 h = (__bf16)f;
  return __builtin_bit_cast(unsigned short, h);
}

__device__ __forceinline__ void gload_lds16(const void* g, void* l) {
  __builtin_amdgcn_global_load_lds((const __attribute__((address_space(1))) void*)g,
                                   (__attribute__((address_space(3))) void*)l,
                                   16, 0, 0);
}

// ---------------- prep kernels ----------------

__global__ __launch_bounds__(256) void convert_x(const float* __restrict__ X,
                                                 unsigned short* __restrict__ Xb,
                                                 int n8) {
  const int stride = gridDim.x * blockDim.x;
  for (int i = blockIdx.x * blockDim.x + threadIdx.x; i < n8; i += stride) {
    const float4 v0 = ((const float4*)X)[(size_t)i * 2 + 0];
    const float4 v1 = ((const float4*)X)[(size_t)i * 2 + 1];
    uint4 w;
    w.x = (uint32_t)f2bf(v0.x) | ((uint32_t)f2bf(v0.y) << 16);
    w.y = (uint32_t)f2bf(v0.z) | ((uint32_t)f2bf(v0.w) << 16);
    w.z = (uint32_t)f2bf(v1.x) | ((uint32_t)f2bf(v1.y) << 16);
    w.w = (uint32_t)f2bf(v1.z) | ((uint32_t)f2bf(v1.w) << 16);
    ((uint4*)Xb)[i] = w;
  }
}

// W (2048x2048 f32, K x N) -> WT (bf16, N x K)
__global__ __launch_bounds__(256) void transpose_cvt(const float* __restrict__ W,
                                                     unsigned short* __restrict__ WT) {
  __shared__ unsigned short tile[64][65];
  const int bx = blockIdx.x * 64;             // N origin
  const int by = blockIdx.y * 64;             // K origin
  const int t  = threadIdx.x;
  const int tr = t >> 4;
  const int tc = (t & 15) * 4;
#pragma unroll
  for (int i = 0; i < 4; ++i) {
    const int r = tr + i * 16;
    const float4 v = *(const float4*)&W[(size_t)(by + r) * 2048 + bx + tc];
    tile[r][tc + 0] = f2bf(v.x);
    tile[r][tc + 1] = f2bf(v.y);
    tile[r][tc + 2] = f2bf(v.z);
    tile[r][tc + 3] = f2bf(v.w);
  }
  __syncthreads();
#pragma unroll
  for (int i = 0; i < 4; ++i) {
    const int a = tr + i * 16;
    ushort4 o;
    o.x = tile[tc + 0][a];
    o.y = tile[tc + 1][a];
    o.z = tile[tc + 2][a];
    o.w = tile[tc + 3][a];
    *(ushort4*)&WT[(size_t)(bx + a) * 2048 + by + tc] = o;
  }
}

// ---------------- fused 256x256 GEMM, K=32 subtiles, quad-buffered ---------
// LDS rows are 64 B (32 bf16). Swizzle: 16B slot s_phys = s_log ^ ((row>>1)&3)
// -> frag reads hit 8 bank-quads x 2 lanes (free). Staged with linear
// gload_lds dest + inverse-swizzled global source (involution both sides).
// Pipeline: subtiles s..s+2 in flight (12 loads/thread); per iter
// s_waitcnt vmcnt(8) -> barrier -> stage s+3 -> 12 ds_read + 32 MFMA.

__global__ __launch_bounds__(512, 2) void qkv_fused9(const unsigned short* __restrict__ Xb,
                                                     const unsigned short* __restrict__ WT,
                                                     float* __restrict__ Out) {
  extern __shared__ char smem[];   // 4 bufs x (A 16KB + B 16KB)

  // XCD-aware swizzle (1536 blocks, 1536 % 8 == 0 -> bijective)
  const int wg  = blockIdx.x;
  const int swz = (wg & 7) * 192 + (wg >> 3);
  const int mb  = swz / 24, nb = swz % 24;
  const int m0  = mb * 256, n0 = nb * 256;

  const int tid  = threadIdx.x;
  const int wave = tid >> 6, lane = tid & 63;
  const int l15  = lane & 15, lg = lane >> 4;
  const int wm   = (wave >> 2) * 128;           // 2 wave-rows
  const int wn   = (wave & 3) * 64;             // 4 wave-cols
  const int s0   = ((lg ^ ((l15 >> 1) & 3)) << 4);  // frag slot byte offset

  const unsigned short* Xp = Xb + (size_t)m0 * 2048;
  const unsigned short* Wp = WT + (size_t)n0 * 2048;

  // staging decomposition: 512 threads, 4 x 16B per subtile (2 A + 2 B)
  const int srow  = tid >> 2;                   // 0..127 (row within 128-row set)
  const int sswz  = ((tid & 3) ^ ((tid >> 3) & 3)) << 3;  // inverse-swizzled k-elem off

  f32x4 acc[8][4] = {};

#define STAGE(S)                                                              \
  do {                                                                        \
    const int kt_ = (S) * 32;                                                 \
    char* base_ = smem + ((S) & 3) * 32768;                                   \
    _Pragma("unroll") for (int i = 0; i < 2; ++i) {                           \
      const int row = i * 128 + srow;                                         \
      gload_lds16(Xp + (size_t)row * 2048 + kt_ + sswz,                       \
                  base_ + i * 8192 + tid * 16);                               \
    }                                                                         \
    _Pragma("unroll") for (int i = 0; i < 2; ++i) {                           \
      const int row = i * 128 + srow;                                         \
      gload_lds16(Wp + (size_t)row * 2048 + kt_ + sswz,                       \
                  base_ + 16384 + i * 8192 + tid * 16);                       \
    }                                                                         \
  } while (0)

#define BODY(S, VMCNT_ASM, DO_STAGE)                                          \
  do {                                                                        \
    asm volatile(VMCNT_ASM ::: "memory");                                     \
    __builtin_amdgcn_s_barrier();                                             \
    if (DO_STAGE) STAGE((S) + 3);                                             \
    const char* Ab_ = smem + ((S) & 3) * 32768;                               \
    const char* Bb_ = Ab_ + 16384;                                            \
    short8 bf[4], af[8];                                                      \
    _Pragma("unroll") for (int ni = 0; ni < 4; ++ni)                          \
      bf[ni] = *(const short8*)(Bb_ + ((wn + ni * 16 + l15) << 6) + s0);      \
    _Pragma("unroll") for (int mi = 0; mi < 8; ++mi)                          \
      af[mi] = *(const short8*)(Ab_ + ((wm + mi * 16 + l15) << 6) + s0);      \
    __builtin_amdgcn_s_setprio(1);                                            \
    _Pragma("unroll") for (int mi = 0; mi < 8; ++mi)                          \
      _Pragma("unroll") for (int ni = 0; ni < 4; ++ni)                        \
        asm("v_mfma_f32_16x16x32_bf16 %0, %1, %2, %0"                         \
            : "+v"(acc[mi][ni])                                               \
            : "v"(af[mi]), "v"(bf[ni]));                                      \
    __builtin_amdgcn_s_setprio(0);                                            \
  } while (0)

  // prologue: stage subtiles 0..2 (12 loads/thread in flight)
  STAGE(0); STAGE(1); STAGE(2);

  for (int s = 0; s < 61; ++s)
    BODY(s, "s_waitcnt vmcnt(8)", 1);
  BODY(61, "s_waitcnt vmcnt(8)", 0);
  BODY(62, "s_waitcnt vmcnt(4)", 0);
  BODY(63, "s_waitcnt vmcnt(0)", 0);

#undef STAGE
#undef BODY

  // epilogue: fused RoPE. C layout: col=lane&15, row=(lane>>4)*4+reg.
#pragma unroll
  for (int ni = 0; ni < 4; ++ni) {
    const int col = n0 + wn + ni * 16 + l15;
    const int sec = col >> 11;                 // 0=q,1=k,2=v
    const int lc  = col & 2047;
    float c = 1.0f, ssg = 0.0f;
    if (sec < 2) {
      const int h = lc >> 7;
      const int p = (lc & 127) >> 1;
      const float theta = exp2f(-(float)p * 0.20762050593046014f); // log2(1e4)/64
      float s;
      sincosf((float)h * theta, &s, &c);
      ssg = (l15 & 1) ? s : -s;
    }
    float* outp = Out + (size_t)sec * 33554432 + lc;
#pragma unroll
    for (int mi = 0; mi < 8; ++mi) {
      const f32x4 a = acc[mi][ni];
#pragma unroll
      for (int r = 0; r < 4; ++r) {
        const float val = a[r];
        float res = val;
        if (sec < 2) {
          const float other = __shfl_xor(val, 1);
          res = val * c + other * ssg;
        }
        __builtin_nontemporal_store(
            res, outp + (size_t)(m0 + wm + mi * 16 + lg * 4 + r) * 2048);
      }
    }
  }
}

// ---------------- fallback GEMM (ws too small) ----------------
__global__ __launch_bounds__(256) void qkv_gemm_small(const float* __restrict__ X,
                                                      const unsigned short* __restrict__ WTl,
                                                      float* __restrict__ Out,
                                                      const int do_rope) {
  __shared__ unsigned short As[128 * 64];
  __shared__ unsigned short Bs[128 * 64];
  const int t    = threadIdx.x;
  const int wave = t >> 6, lane = t & 63;
  const int l15  = lane & 15, lg = lane >> 4;
  const int wm   = (wave >> 1) * 64;
  const int wn   = (wave & 1) * 64;
  const int m0   = blockIdx.y * 128;
  const int n0   = blockIdx.x * 128;

  f32x4 acc[4][4] = {};

  for (int kt = 0; kt < 2048; kt += 64) {
#pragma unroll
    for (int i = 0; i < 8; ++i) {
      const int f = i * 256 + t;
      const int row = f >> 4, chunk = f & 15;
      const float4 v = *(const float4*)&X[(size_t)(m0 + row) * 2048 + kt + chunk * 4];
      const uint32_t lo = (uint32_t)f2bf(v.x) | ((uint32_t)f2bf(v.y) << 16);
      const uint32_t hi = (uint32_t)f2bf(v.z) | ((uint32_t)f2bf(v.w) << 16);
      const int slot = chunk >> 1;
      const int off  = row * 128 + (((slot ^ (row & 7)) << 4) | ((chunk & 1) << 3));
      uint2* p = (uint2*)((char*)As + off);
      p->x = lo; p->y = hi;
    }
#pragma unroll
    for (int i = 0; i < 4; ++i) {
      const int seg = i * 4 + wave;
      const int row = seg * 8 + (lane >> 3);
      const int ps  = lane & 7;
      const int ss  = ps ^ (row & 7);
      gload_lds16(WTl + (size_t)(n0 + row) * 2048 + kt + ss * 8,
                  (char*)Bs + seg * 1024 + lane * 16);
    }
    __syncthreads();
#pragma unroll
    for (int kk = 0; kk < 2; ++kk) {
      short8 afr[4], bfr[4];
#pragma unroll
      for (int mi = 0; mi < 4; ++mi) {
        const int row  = wm + mi * 16 + l15;
        const int slot = kk * 4 + lg;
        afr[mi] = *(const short8*)((const char*)As + row * 128 + ((slot ^ (row & 7)) << 4));
      }
#pragma unroll
      for (int ni = 0; ni < 4; ++ni) {
        const int row  = wn + ni * 16 + l15;
        const int slot = kk * 4 + lg;
        bfr[ni] = *(const short8*)((const char*)Bs + row * 128 + ((slot ^ (row & 7)) << 4));
      }
#pragma unroll
      for (int mi = 0; mi < 4; ++mi)
#pragma unroll
        for (int ni = 0; ni < 4; ++ni)
          asm("v_mfma_f32_16x16x32_bf16 %0, %1, %2, %0"
              : "+v"(acc[mi][ni])
              : "v"(afr[mi]), "v"(bfr[ni]));
    }
    __syncthreads();
  }

#pragma unroll
  for (int ni = 0; ni < 4; ++ni) {
    const int col = n0 + wn + ni * 16 + l15;
    float c = 1.0f, ssg = 0.0f;
    if (do_rope) {
      const int h = col >> 7;
      const int p = (col & 127) >> 1;
      const float theta = exp2f(-(float)p * 0.20762050593046014f);
      float s;
      sincosf((float)h * theta, &s, &c);
      ssg = (l15 & 1) ? s : -s;
    }
#pragma unroll
    for (int mi = 0; mi < 4; ++mi) {
      const f32x4 a = acc[mi][ni];
#pragma unroll
      for (int r = 0; r < 4; ++r) {
        const float val = a[r];
        float res = val;
        if (do_rope) {
          const float other = __shfl_xor(val, 1);
          res = val * c + other * ssg;
        }
        Out[(size_t)(m0 + wm + mi * 16 + lg * 4 + r) * 2048 + col] = res;
      }
    }
  }
}

extern "C" void kernel_launch(void* const* d_in, const int* in_sizes, int n_in,
                              void* d_out, int out_size, void* d_ws, size_t ws_size,
                              hipStream_t stream) {
  (void)in_sizes; (void)n_in; (void)out_size;
  const float* x  = (const float*)d_in[0];
  const float* Wq = (const float*)d_in[1];
  const float* Wk = (const float*)d_in[2];
  const float* Wv = (const float*)d_in[3];
  float* out = (float*)d_out;

  const size_t XB_ELEMS = 16384ull * 2048;
  const size_t WT_ELEMS = 6144ull * 2048;
  dim3 tb(256), tg(32, 32);

  if (ws_size >= (XB_ELEMS + WT_ELEMS) * sizeof(unsigned short)) {
    unsigned short* Xb  = (unsigned short*)d_ws;
    unsigned short* WTf = Xb + XB_ELEMS;
    convert_x<<<2048, 256, 0, stream>>>(x, Xb, (int)(XB_ELEMS / 8));
    transpose_cvt<<<tg, tb, 0, stream>>>(Wq, WTf);
    transpose_cvt<<<tg, tb, 0, stream>>>(Wk, WTf + 2048ull * 2048);
    transpose_cvt<<<tg, tb, 0, stream>>>(Wv, WTf + 2ull * 2048 * 2048);
    hipFuncSetAttribute((const void*)qkv_fused9,
                        hipFuncAttributeMaxDynamicSharedMemorySize, 131072);
    qkv_fused9<<<1536, 512, 131072, stream>>>(Xb, WTf, out);
  } else {
    unsigned short* WqT = (unsigned short*)d_ws;
    unsigned short* WkT = WqT + 2048ull * 2048;
    unsigned short* WvT = WkT + 2048ull * 2048;
    transpose_cvt<<<tg, tb, 0, stream>>>(Wq, WqT);
    transpose_cvt<<<tg, tb, 0, stream>>>(Wk, WkT);
    transpose_cvt<<<tg, tb, 0, stream>>>(Wv, WvT);
    dim3 gg(16, 128);
    qkv_gemm_small<<<gg, tb, 0, stream>>>(x, WqT, out,            1);
    qkv_gemm_small<<<gg, tb, 0, stream>>>(x, WkT, out + 33554432, 1);
    qkv_gemm_small<<<gg, tb, 0, stream>>>(x, WvT, out + 67108864, 0);
  }
}

// Round 5
// 444.994 us; speedup vs baseline: 1.5573x; 1.0072x over previous
//
#include <hip/hip_runtime.h>
#include <hip/hip_bf16.h>
#include <stdint.h>

// ---------------------------------------------------------------------------
// SelfAttention QKV projection + head-indexed RoPE, MI355X (gfx950)
//   q = rope(x @ Wq), k = rope(x @ Wk), v = x @ Wv   (pos = head index!)
// Round 5: 8-phase schedule (m201 port). Fused GEMM (M=16384,N=6144,K=2048),
//   256x256 tile, BK=64, 8 waves (2Mx4N), 2x64KiB LDS buffers.
//   Per phase: {ds_read frag subtile, 2x global_load_lds, barrier,
//   lgkmcnt(0)+sched_barrier, setprio(1), 16 MFMA, setprio(0), barrier}.
//   One counted vmcnt(4) gate per K-tile (never drain-0 mid-loop).
//   XOR bank swizzle (0-conflict, proven r3/r4), XCD swizzle, fused RoPE.
// ---------------------------------------------------------------------------

typedef __attribute__((ext_vector_type(8))) short short8;
typedef __attribute__((ext_vector_type(4))) float f32x4;

__device__ __forceinline__ unsigned short f2bf(float f) {
  __bf16 h = (__bf16)f;
  return __builtin_bit_cast(unsigned short, h);
}

__device__ __forceinline__ void gload_lds16(const void* g, void* l) {
  __builtin_amdgcn_global_load_lds((const __attribute__((address_space(1))) void*)g,
                                   (__attribute__((address_space(3))) void*)l,
                                   16, 0, 0);
}

// ---------------- prep kernels ----------------

__global__ __launch_bounds__(256) void convert_x(const float* __restrict__ X,
                                                 unsigned short* __restrict__ Xb,
                                                 int n8) {
  const int stride = gridDim.x * blockDim.x;
  for (int i = blockIdx.x * blockDim.x + threadIdx.x; i < n8; i += stride) {
    const float4 v0 = ((const float4*)X)[(size_t)i * 2 + 0];
    const float4 v1 = ((const float4*)X)[(size_t)i * 2 + 1];
    uint4 w;
    w.x = (uint32_t)f2bf(v0.x) | ((uint32_t)f2bf(v0.y) << 16);
    w.y = (uint32_t)f2bf(v0.z) | ((uint32_t)f2bf(v0.w) << 16);
    w.z = (uint32_t)f2bf(v1.x) | ((uint32_t)f2bf(v1.y) << 16);
    w.w = (uint32_t)f2bf(v1.z) | ((uint32_t)f2bf(v1.w) << 16);
    ((uint4*)Xb)[i] = w;
  }
}

// W (2048x2048 f32, K x N) -> WT (bf16, N x K)
__global__ __launch_bounds__(256) void transpose_cvt(const float* __restrict__ W,
                                                     unsigned short* __restrict__ WT) {
  __shared__ unsigned short tile[64][65];
  const int bx = blockIdx.x * 64;             // N origin
  const int by = blockIdx.y * 64;             // K origin
  const int t  = threadIdx.x;
  const int tr = t >> 4;
  const int tc = (t & 15) * 4;
#pragma unroll
  for (int i = 0; i < 4; ++i) {
    const int r = tr + i * 16;
    const float4 v = *(const float4*)&W[(size_t)(by + r) * 2048 + bx + tc];
    tile[r][tc + 0] = f2bf(v.x);
    tile[r][tc + 1] = f2bf(v.y);
    tile[r][tc + 2] = f2bf(v.z);
    tile[r][tc + 3] = f2bf(v.w);
  }
  __syncthreads();
#pragma unroll
  for (int i = 0; i < 4; ++i) {
    const int a = tr + i * 16;
    ushort4 o;
    o.x = tile[tc + 0][a];
    o.y = tile[tc + 1][a];
    o.z = tile[tc + 2][a];
    o.w = tile[tc + 3][a];
    *(ushort4*)&WT[(size_t)(bx + a) * 2048 + by + tc] = o;
  }
}

// ---------------- fused 256x256 GEMM, BK=64, 8-phase schedule --------------
// LDS: buf b at b*64KiB: A[256][64] then B[256][64] (128B rows).
// Swizzle: 16B slot s_phys = s_log ^ (row&7); frag byte = s0 ^ (kk<<6),
// s0 = (lg ^ (l15&7))<<4. Staged linear-dest + inverse-swizzled source.
// Staging: A(t+1) in ph0/ph1 (dest buffer's A idle during tile t);
//          B(t+2) in ph2/ph3 (own buffer's B fully read at ph0).
// Gate: vmcnt(4) at ph3 end (in-order retirement => A(t+1),B(t+1) done).

__global__ __launch_bounds__(512, 2) void qkv_fused10(const unsigned short* __restrict__ Xb,
                                                      const unsigned short* __restrict__ WT,
                                                      float* __restrict__ Out) {
  extern __shared__ char smem[];

  // XCD-aware swizzle (1536 blocks, 1536 % 8 == 0 -> bijective)
  const int wg  = blockIdx.x;
  const int swz = (wg & 7) * 192 + (wg >> 3);
  const int mb  = swz / 24, nb = swz % 24;
  const int m0  = mb * 256, n0 = nb * 256;

  const int tid  = threadIdx.x;
  const int wave = tid >> 6, lane = tid & 63;
  const int l15  = lane & 15, lg = lane >> 4;
  const int wm   = (wave >> 2) * 128;          // 2 wave-rows
  const int wn   = (wave & 3) * 64;            // 4 wave-cols
  const int s0   = ((lg ^ (l15 & 7)) << 4);    // kk0 frag slot; kk1 = s0^64

  const unsigned short* Xp = Xb + (size_t)m0 * 2048;
  const unsigned short* Wp = WT + (size_t)n0 * 2048;

  const int srow  = tid >> 3;                  // 0..63
  const int sslot = tid & 7;                   // physical 16B slot

  f32x4 acc[8][4] = {};

#define GLD_A(TP1, H)                                                         \
  do {                                                                        \
    char* dst_ = smem + (((TP1) & 1) << 16) + ((H) << 14);                    \
    _Pragma("unroll") for (int i_ = 0; i_ < 2; ++i_) {                        \
      const int row_ = (H) * 128 + i_ * 64 + srow;                            \
      gload_lds16(Xp + (size_t)row_ * 2048 + (TP1) * 64 +                     \
                      ((sslot ^ (row_ & 7)) << 3),                            \
                  dst_ + i_ * 8192 + tid * 16);                               \
    }                                                                         \
  } while (0)

#define GLD_B(TP2, H)                                                         \
  do {                                                                        \
    char* dst_ = smem + (((TP2) & 1) << 16) + 32768 + ((H) << 14);            \
    _Pragma("unroll") for (int i_ = 0; i_ < 2; ++i_) {                        \
      const int row_ = (H) * 128 + i_ * 64 + srow;                            \
      gload_lds16(Wp + (size_t)row_ * 2048 + (TP2) * 64 +                     \
                      ((sslot ^ (row_ & 7)) << 3),                            \
                  dst_ + i_ * 8192 + tid * 16);                               \
    }                                                                         \
  } while (0)

#define LDA4(MH, KS)                                                          \
  _Pragma("unroll") for (int mi_ = 0; mi_ < 4; ++mi_)                         \
      af[mi_] = *(const short8*)(Ab + ((wm + (MH) * 64 + mi_ * 16 + l15) << 7)\
                                  + (s0 ^ ((KS) << 6)));

#define PHASE_SYNC                                                            \
  __builtin_amdgcn_s_barrier();                                               \
  asm volatile("s_waitcnt lgkmcnt(0)" ::: "memory");                          \
  __builtin_amdgcn_sched_barrier(0);

#define MFMA16(MH, KS)                                                        \
  do {                                                                        \
    __builtin_amdgcn_s_setprio(1);                                            \
    _Pragma("unroll") for (int mi_ = 0; mi_ < 4; ++mi_)                       \
      _Pragma("unroll") for (int ni_ = 0; ni_ < 4; ++ni_)                     \
        asm("v_mfma_f32_16x16x32_bf16 %0, %1, %2, %0"                         \
            : "+v"(acc[(MH) * 4 + mi_][ni_])                                  \
            : "v"(af[mi_]), "v"(bfr[ni_][KS]));                               \
    __builtin_amdgcn_s_setprio(0);                                            \
  } while (0)

  // prologue: A(0), B(0), B(1); gate leaves B(1)'s 4 loads in flight
  GLD_A(0, 0); GLD_A(0, 1);
  GLD_B(0, 0); GLD_B(0, 1);
  GLD_B(1, 0); GLD_B(1, 1);
  asm volatile("s_waitcnt vmcnt(4)" ::: "memory");
  __builtin_amdgcn_s_barrier();

  for (int t = 0; t < 32; ++t) {
    const char* Ab = smem + ((t & 1) << 16);
    const char* Bb = Ab + 32768;
    short8 bfr[4][2], af[4];

    // ----- ph0: B all + A(mh0,kk0); stage A(t+1) half0 -----
#pragma unroll
    for (int ni_ = 0; ni_ < 4; ++ni_) {
      const char* p_ = Bb + ((wn + ni_ * 16 + l15) << 7);
      bfr[ni_][0] = *(const short8*)(p_ + s0);
      bfr[ni_][1] = *(const short8*)(p_ + (s0 ^ 64));
    }
    LDA4(0, 0);
    if (t < 31) GLD_A(t + 1, 0);
    PHASE_SYNC;
    MFMA16(0, 0);
    __builtin_amdgcn_s_barrier();

    // ----- ph1: A(mh1,kk0); stage A(t+1) half1 -----
    LDA4(1, 0);
    if (t < 31) GLD_A(t + 1, 1);
    PHASE_SYNC;
    MFMA16(1, 0);
    __builtin_amdgcn_s_barrier();

    // ----- ph2: A(mh0,kk1); stage B(t+2) half0 -----
    LDA4(0, 1);
    if (t < 30) GLD_B(t + 2, 0);
    PHASE_SYNC;
    MFMA16(0, 1);
    __builtin_amdgcn_s_barrier();

    // ----- ph3: A(mh1,kk1); stage B(t+2) half1; tile-end gate -----
    LDA4(1, 1);
    if (t < 30) GLD_B(t + 2, 1);
    PHASE_SYNC;
    MFMA16(1, 1);
    if (t == 30)     asm volatile("s_waitcnt vmcnt(0)" ::: "memory");
    else if (t < 30) asm volatile("s_waitcnt vmcnt(4)" ::: "memory");
    __builtin_amdgcn_s_barrier();
  }

#undef GLD_A
#undef GLD_B
#undef LDA4
#undef PHASE_SYNC
#undef MFMA16

  // epilogue: fused RoPE. C layout: col=lane&15, row=(lane>>4)*4+reg.
#pragma unroll
  for (int ni = 0; ni < 4; ++ni) {
    const int col = n0 + wn + ni * 16 + l15;
    const int sec = col >> 11;                 // 0=q,1=k,2=v
    const int lc  = col & 2047;
    float c = 1.0f, ssg = 0.0f;
    if (sec < 2) {
      const int h = lc >> 7;
      const int p = (lc & 127) >> 1;
      const float theta = exp2f(-(float)p * 0.20762050593046014f); // log2(1e4)/64
      float s;
      sincosf((float)h * theta, &s, &c);
      ssg = (l15 & 1) ? s : -s;
    }
    float* outp = Out + (size_t)sec * 33554432 + lc;
#pragma unroll
    for (int mi = 0; mi < 8; ++mi) {
      const f32x4 a = acc[mi][ni];
#pragma unroll
      for (int r = 0; r < 4; ++r) {
        const float val = a[r];
        float res = val;
        if (sec < 2) {
          const float other = __shfl_xor(val, 1);
          res = val * c + other * ssg;
        }
        __builtin_nontemporal_store(
            res, outp + (size_t)(m0 + wm + mi * 16 + lg * 4 + r) * 2048);
      }
    }
  }
}

// ---------------- fallback GEMM (ws too small) ----------------
__global__ __launch_bounds__(256) void qkv_gemm_small(const float* __restrict__ X,
                                                      const unsigned short* __restrict__ WTl,
                                                      float* __restrict__ Out,
                                                      const int do_rope) {
  __shared__ unsigned short As[128 * 64];
  __shared__ unsigned short Bs[128 * 64];
  const int t    = threadIdx.x;
  const int wave = t >> 6, lane = t & 63;
  const int l15  = lane & 15, lg = lane >> 4;
  const int wm   = (wave >> 1) * 64;
  const int wn   = (wave & 1) * 64;
  const int m0   = blockIdx.y * 128;
  const int n0   = blockIdx.x * 128;

  f32x4 acc[4][4] = {};

  for (int kt = 0; kt < 2048; kt += 64) {
#pragma unroll
    for (int i = 0; i < 8; ++i) {
      const int f = i * 256 + t;
      const int row = f >> 4, chunk = f & 15;
      const float4 v = *(const float4*)&X[(size_t)(m0 + row) * 2048 + kt + chunk * 4];
      const uint32_t lo = (uint32_t)f2bf(v.x) | ((uint32_t)f2bf(v.y) << 16);
      const uint32_t hi = (uint32_t)f2bf(v.z) | ((uint32_t)f2bf(v.w) << 16);
      const int slot = chunk >> 1;
      const int off  = row * 128 + (((slot ^ (row & 7)) << 4) | ((chunk & 1) << 3));
      uint2* p = (uint2*)((char*)As + off);
      p->x = lo; p->y = hi;
    }
#pragma unroll
    for (int i = 0; i < 4; ++i) {
      const int seg = i * 4 + wave;
      const int row = seg * 8 + (lane >> 3);
      const int ps  = lane & 7;
      const int ss  = ps ^ (row & 7);
      gload_lds16(WTl + (size_t)(n0 + row) * 2048 + kt + ss * 8,
                  (char*)Bs + seg * 1024 + lane * 16);
    }
    __syncthreads();
#pragma unroll
    for (int kk = 0; kk < 2; ++kk) {
      short8 afr[4], bfr[4];
#pragma unroll
      for (int mi = 0; mi < 4; ++mi) {
        const int row  = wm + mi * 16 + l15;
        const int slot = kk * 4 + lg;
        afr[mi] = *(const short8*)((const char*)As + row * 128 + ((slot ^ (row & 7)) << 4));
      }
#pragma unroll
      for (int ni = 0; ni < 4; ++ni) {
        const int row  = wn + ni * 16 + l15;
        const int slot = kk * 4 + lg;
        bfr[ni] = *(const short8*)((const char*)Bs + row * 128 + ((slot ^ (row & 7)) << 4));
      }
#pragma unroll
      for (int mi = 0; mi < 4; ++mi)
#pragma unroll
        for (int ni = 0; ni < 4; ++ni)
          asm("v_mfma_f32_16x16x32_bf16 %0, %1, %2, %0"
              : "+v"(acc[mi][ni])
              : "v"(afr[mi]), "v"(bfr[ni]));
    }
    __syncthreads();
  }

#pragma unroll
  for (int ni = 0; ni < 4; ++ni) {
    const int col = n0 + wn + ni * 16 + l15;
    float c = 1.0f, ssg = 0.0f;
    if (do_rope) {
      const int h = col >> 7;
      const int p = (col & 127) >> 1;
      const float theta = exp2f(-(float)p * 0.20762050593046014f);
      float s;
      sincosf((float)h * theta, &s, &c);
      ssg = (l15 & 1) ? s : -s;
    }
#pragma unroll
    for (int mi = 0; mi < 4; ++mi) {
      const f32x4 a = acc[mi][ni];
#pragma unroll
      for (int r = 0; r < 4; ++r) {
        const float val = a[r];
        float res = val;
        if (do_rope) {
          const float other = __shfl_xor(val, 1);
          res = val * c + other * ssg;
        }
        Out[(size_t)(m0 + wm + mi * 16 + lg * 4 + r) * 2048 + col] = res;
      }
    }
  }
}

extern "C" void kernel_launch(void* const* d_in, const int* in_sizes, int n_in,
                              void* d_out, int out_size, void* d_ws, size_t ws_size,
                              hipStream_t stream) {
  (void)in_sizes; (void)n_in; (void)out_size;
  const float* x  = (const float*)d_in[0];
  const float* Wq = (const float*)d_in[1];
  const float* Wk = (const float*)d_in[2];
  const float* Wv = (const float*)d_in[3];
  float* out = (float*)d_out;

  const size_t XB_ELEMS = 16384ull * 2048;
  const size_t WT_ELEMS = 6144ull * 2048;
  dim3 tb(256), tg(32, 32);

  if (ws_size >= (XB_ELEMS + WT_ELEMS) * sizeof(unsigned short)) {
    unsigned short* Xb  = (unsigned short*)d_ws;
    unsigned short* WTf = Xb + XB_ELEMS;
    convert_x<<<2048, 256, 0, stream>>>(x, Xb, (int)(XB_ELEMS / 8));
    transpose_cvt<<<tg, tb, 0, stream>>>(Wq, WTf);
    transpose_cvt<<<tg, tb, 0, stream>>>(Wk, WTf + 2048ull * 2048);
    transpose_cvt<<<tg, tb, 0, stream>>>(Wv, WTf + 2ull * 2048 * 2048);
    hipFuncSetAttribute((const void*)qkv_fused10,
                        hipFuncAttributeMaxDynamicSharedMemorySize, 131072);
    qkv_fused10<<<1536, 512, 131072, stream>>>(Xb, WTf, out);
  } else {
    unsigned short* WqT = (unsigned short*)d_ws;
    unsigned short* WkT = WqT + 2048ull * 2048;
    unsigned short* WvT = WkT + 2048ull * 2048;
    transpose_cvt<<<tg, tb, 0, stream>>>(Wq, WqT);
    transpose_cvt<<<tg, tb, 0, stream>>>(Wk, WkT);
    transpose_cvt<<<tg, tb, 0, stream>>>(Wv, WvT);
    dim3 gg(16, 128);
    qkv_gemm_small<<<gg, tb, 0, stream>>>(x, WqT, out,            1);
    qkv_gemm_small<<<gg, tb, 0, stream>>>(x, WkT, out + 33554432, 1);
    qkv_gemm_small<<<gg, tb, 0, stream>>>(x, WvT, out + 67108864, 0);
  }
}